// Round 11
// baseline (18499.768 us; speedup 1.0000x reference)
//
#include <hip/hip_runtime.h>
#include <hip/hip_cooperative_groups.h>
#include <math.h>

namespace cg = cooperative_groups;

#define NB 32      // batch
#define NF 512     // feature_size
#define ND 256     // d_model
#define NT 32      // decode steps
#define RPB 32     // rows per attention tile
#define NTILE (NF / RPB)   // 16
#define NBLK (NB * NTILE)  // 512

typedef __attribute__((ext_vector_type(8))) short bf16x8;
typedef __attribute__((ext_vector_type(4))) float f32x4;

__device__ __forceinline__ float sigmoidf_(float x) { return 1.0f / (1.0f + __expf(-x)); }

__device__ __forceinline__ short f2bf(float x) {
    union { float f; unsigned u; } v; v.f = x;
    unsigned r = (v.u + 0x7FFF + ((v.u >> 16) & 1)) >> 16;
    return (short)r;
}

// ---------------- positional encoding q[F][D] ----------------
__global__ void pe_kernel(float* __restrict__ q) {
    int p = blockIdx.x;
    int d = threadIdx.x;
    float i2 = (float)((d >> 1) << 1);
    float rate = expf(-9.210340371976184f * (i2 / (float)ND));
    float ang = (float)p * rate;
    q[p * ND + d] = (d & 1) ? cosf(ang) : sinf(ang);
}

// ---------------- fp32 -> bf16 weight convert ----------------
__global__ void wcvt_kernel(const float* __restrict__ w, short* __restrict__ wb, int n) {
    int i = blockIdx.x * 256 + threadIdx.x;
    if (i < n) wb[i] = f2bf(w[i]);
}

// ---------------- transposes: w_hT[k][o], w_gT[k][o] ----------------
__global__ void wprep_kernel(const float* __restrict__ w_h, const float* __restrict__ w_g,
                             float* __restrict__ w_hT, float* __restrict__ w_gT) {
    int k = blockIdx.x;      // 0..511
    int o = threadIdx.x;     // 0..255
    if (k < ND) w_hT[(size_t)k * ND + o] = w_h[(size_t)o * ND + k];
    w_gT[(size_t)k * ND + o] = w_g[(size_t)o * 512 + k];
}

// ---------------- qwq[p][o] = dot(q[p,:], w_q[o,:]) ----------------
__global__ void qwq_kernel(const float* __restrict__ q, const float* __restrict__ w_q,
                           float* __restrict__ qwq) {
    int p = blockIdx.x;
    int o = threadIdx.x;
    __shared__ float qs[ND];
    qs[o] = q[(size_t)p * ND + o];
    __syncthreads();
    const float4* wr = (const float4*)(w_q + (size_t)o * ND);
    float acc = 0.f;
    for (int k4 = 0; k4 < ND / 4; ++k4) {
        float4 w = wr[k4];
        int k = 4 * k4;
        acc += qs[k] * w.x + qs[k + 1] * w.y + qs[k + 2] * w.z + qs[k + 3] * w.w;
    }
    qwq[(size_t)p * ND + o] = acc;
}

// ---------------- bsum = f@w_f^T + qwq ----------------
__global__ void base_kernel(const float* __restrict__ fin, const float* __restrict__ w_f,
                            const float* __restrict__ qwq, float* __restrict__ bsum) {
    int b = blockIdx.x / NTILE;
    int f0 = (blockIdx.x % NTILE) * RPB;
    int o = threadIdx.x;
    __shared__ float fs[RPB][ND];
    #pragma unroll
    for (int r = 0; r < RPB; ++r)
        fs[r][o] = fin[((size_t)(b * NF + f0 + r)) * ND + o];
    __syncthreads();
    float acc[RPB];
    #pragma unroll
    for (int r = 0; r < RPB; ++r) acc[r] = 0.f;
    const float4* wr = (const float4*)(w_f + (size_t)o * ND);
    for (int k4 = 0; k4 < ND / 4; ++k4) {
        float4 w = wr[k4];
        int k = 4 * k4;
        #pragma unroll
        for (int r = 0; r < RPB; ++r)
            acc[r] += fs[r][k] * w.x + fs[r][k + 1] * w.y + fs[r][k + 2] * w.z + fs[r][k + 3] * w.w;
    }
    #pragma unroll
    for (int r = 0; r < RPB; ++r)
        bsum[((size_t)(b * NF + f0 + r)) * ND + o] = acc[r] + qwq[(size_t)(f0 + r) * ND + o];
}

// ---------------- decoder step kernel (persistent-cooperative OR per-stage launches) ----------------
// Stages per step t:
//  R  (blocks 0-31)  : csum/cpsum reduce, build ZT[k][b] (transposed) and ZP[b][512]
//  GP (blocks 0-127) : gates GEMM (weights-once: 2 cols x 4 gates/block) + LSTM pointwise -> h, cell
//  H  (blocks 0-31 hwh; 32-63 pred(t-1))
//  A  (all 512)      : MFMA attention (phases 1-7), updates bsum, cpart, cppart
__global__ void __launch_bounds__(256, 2) dec_step(
        int coop, int t0, int smask,
        const float* __restrict__ fin, const int* __restrict__ ids,
        const float* __restrict__ emb, const float* __restrict__ qpe,
        float* __restrict__ bsum,
        const float* __restrict__ w_ih, const float* __restrict__ w_hh,
        const float* __restrict__ w_hT, const float* __restrict__ w_gT,
        const short* __restrict__ w_e_bf, const short* __restrict__ w_s_bf,
        float* __restrict__ h, float* __restrict__ cell, float* __restrict__ hwh,
        float* __restrict__ ZT, float* __restrict__ ZP,
        float* __restrict__ cpart, float* __restrict__ cppart,
        float* __restrict__ out) {
    cg::grid_group grid = cg::this_grid();
    int bid = blockIdx.x;
    int tid = threadIdx.x;
    int l = tid & 63;
    int wv = tid >> 6;
    int c15 = l & 15;
    int g = l >> 4;

    __shared__ __align__(16) short tin_bf[RPB * ND];   // 16 KB
    __shared__ float xfer[RPB * 257];                  // 32.9 KB (aliased by GP/H stages)
    __shared__ float sred[RPB][5];
    char* tb = (char*)tin_bf;

    int ab = bid / NTILE;
    int tile = bid % NTILE;
    int f0 = tile * RPB;
    int o0 = wv * 64;

    int tbeg = coop ? 0 : t0;
    int tend = coop ? NT : t0;

    for (int t = tbeg; t <= tend; ++t) {
        // ================= stage R =================
        if ((smask & 1) && bid < NB) {
            int b = bid;
            float csum = 0.f, cpsum = 0.f;
            if (t > 0) {
                #pragma unroll
                for (int tl = 0; tl < NTILE; ++tl) {
                    csum  += cpart [((size_t)tl * NB + b) * ND + tid];
                    cpsum += cppart[((size_t)tl * NB + b) * ND + tid];
                }
            }
            float hv = h[(size_t)b * ND + tid];
            if (t < NT) {
                float xv = emb[(size_t)ids[b * NT + t] * ND + tid];
                ZT[(size_t)tid * NB + b]            = xv;
                ZT[(size_t)(ND + tid) * NB + b]     = cpsum;
                ZT[(size_t)(2 * ND + tid) * NB + b] = hv;
            }
            ZP[(size_t)b * 512 + tid]      = csum;
            ZP[(size_t)b * 512 + ND + tid] = hv;
        }
        if (coop) grid.sync();

        // ================= stage GP =================
        if ((smask & 2) && t < NT && bid < 128) {
            int o2 = bid * 2;
            int b = tid & 31;
            int row = tid >> 5;          // row = gate*2 + oo
            int gt = row >> 1, oo = row & 1;
            int j = gt * ND + o2 + oo;
            const float* wi = w_ih + (size_t)j * 512;
            const float* wh = w_hh + (size_t)j * ND;
            float acc = 0.f;
            #pragma unroll 8
            for (int k = 0; k < 512; ++k) acc += wi[k] * ZT[(size_t)k * NB + b];
            #pragma unroll 8
            for (int k = 0; k < 256; ++k) acc += wh[k] * ZT[(size_t)(512 + k) * NB + b];
            float* gacc = xfer;          // [8][32]
            gacc[row * NB + b] = acc;
            __syncthreads();
            if (tid < 64) {
                int b2 = tid & 31, oo2 = tid >> 5;
                int o = o2 + oo2;
                float gi = gacc[(0 * 2 + oo2) * NB + b2];
                float gf = gacc[(1 * 2 + oo2) * NB + b2];
                float gG = gacc[(2 * 2 + oo2) * NB + b2];
                float go = gacc[(3 * 2 + oo2) * NB + b2];
                float cold = cell[(size_t)b2 * ND + o];
                float cnew = sigmoidf_(gf) * cold + sigmoidf_(gi) * tanhf(gG);
                float hval = sigmoidf_(go) * tanhf(cnew);
                cell[(size_t)b2 * ND + o] = cnew;
                h[(size_t)b2 * ND + o] = hval;
            }
        }
        if (coop) grid.sync();

        // ================= stage H =================
        if (smask & 4) {
            if (bid < NB) {
                if (t < NT) {
                    int b = bid;
                    float* hn = xfer;
                    hn[tid] = h[(size_t)b * ND + tid];
                    __syncthreads();
                    float a = 0.f;
                    #pragma unroll 8
                    for (int k = 0; k < ND; ++k)
                        a += hn[k] * w_hT[(size_t)k * ND + tid];
                    hwh[(size_t)b * ND + tid] = a;
                }
            } else if (bid < 2 * NB) {
                if (t > 0) {
                    int b = bid - NB;
                    float* zp = xfer;
                    zp[tid] = ZP[(size_t)b * 512 + tid];
                    zp[ND + tid] = ZP[(size_t)b * 512 + ND + tid];
                    __syncthreads();
                    float p = 0.f;
                    #pragma unroll 8
                    for (int k = 0; k < 512; ++k)
                        p += zp[k] * w_gT[(size_t)k * ND + tid];
                    out[((size_t)b * NT + (t - 1)) * ND + tid] = p;
                }
            }
        }
        if (coop) grid.sync();
        if (t >= NT) break;

        // ================= stage A =================
        if (smask & 8) {
            int b = ab;
            float hwh_reg = hwh[(size_t)b * ND + tid];

            // phase 1: tin = tanh(hwh + bsum) -> bf16 swizzled LDS
            #pragma unroll
            for (int r = 0; r < RPB; ++r) {
                float bs = bsum[((size_t)(b * NF + f0 + r)) * ND + tid];
                int byte = (r * 512 + tid * 2) ^ ((r & 7) << 4);
                *(short*)(tb + byte) = f2bf(tanhf(hwh_reg + bs));
            }
            __syncthreads();

            // phase 2: e = tin @ w_e^T
            f32x4 acc[2][4];
            #pragma unroll
            for (int mt = 0; mt < 2; ++mt)
                #pragma unroll
                for (int nt = 0; nt < 4; ++nt)
                    acc[mt][nt] = (f32x4)0.f;
            #pragma unroll
            for (int ks = 0; ks < 8; ++ks) {
                int kb = ks * 32 + g * 8;
                bf16x8 afr[2];
                #pragma unroll
                for (int mt = 0; mt < 2; ++mt) {
                    int row = mt * 16 + c15;
                    int byte = (row * 512 + kb * 2) ^ ((row & 7) << 4);
                    afr[mt] = *(const bf16x8*)(tb + byte);
                }
                #pragma unroll
                for (int nt = 0; nt < 4; ++nt) {
                    int o = o0 + nt * 16 + c15;
                    bf16x8 bfr = *(const bf16x8*)(w_e_bf + (size_t)o * ND + kb);
                    #pragma unroll
                    for (int mt = 0; mt < 2; ++mt)
                        acc[mt][nt] = __builtin_amdgcn_mfma_f32_16x16x32_bf16(afr[mt], bfr, acc[mt][nt], 0, 0, 0);
                }
            }

            // phase 3: in-register softmax over cols
            {
                float ps[2][4];
                #pragma unroll
                for (int mt = 0; mt < 2; ++mt)
                    #pragma unroll
                    for (int reg = 0; reg < 4; ++reg) ps[mt][reg] = 0.f;
                #pragma unroll
                for (int mt = 0; mt < 2; ++mt)
                    #pragma unroll
                    for (int nt = 0; nt < 4; ++nt)
                        #pragma unroll
                        for (int reg = 0; reg < 4; ++reg) {
                            float a = __expf(acc[mt][nt][reg]);
                            acc[mt][nt][reg] = a;
                            ps[mt][reg] += a;
                        }
                #pragma unroll
                for (int off = 1; off <= 8; off <<= 1)
                    #pragma unroll
                    for (int mt = 0; mt < 2; ++mt)
                        #pragma unroll
                        for (int reg = 0; reg < 4; ++reg)
                            ps[mt][reg] += __shfl_xor(ps[mt][reg], off);
                if (c15 == 0) {
                    #pragma unroll
                    for (int mt = 0; mt < 2; ++mt)
                        #pragma unroll
                        for (int reg = 0; reg < 4; ++reg)
                            sred[mt * 16 + g * 4 + reg][wv] = ps[mt][reg];
                }
                __syncthreads();
                #pragma unroll
                for (int mt = 0; mt < 2; ++mt)
                    #pragma unroll
                    for (int reg = 0; reg < 4; ++reg) {
                        int r = mt * 16 + g * 4 + reg;
                        float inv = 1.0f / (sred[r][0] + sred[r][1] + sred[r][2] + sred[r][3]);
                        #pragma unroll
                        for (int nt = 0; nt < 4; ++nt)
                            acc[mt][nt][reg] *= inv;
                    }
            }

            // phase 4: alpha C-layout -> xfer
            #pragma unroll
            for (int mt = 0; mt < 2; ++mt)
                #pragma unroll
                for (int reg = 0; reg < 4; ++reg) {
                    int r = mt * 16 + g * 4 + reg;
                    #pragma unroll
                    for (int nt = 0; nt < 4; ++nt)
                        xfer[r * 257 + o0 + nt * 16 + c15] = acc[mt][nt][reg];
                }
            __syncthreads();

            // phase 5: c/cp partials col-parallel; alpha -> bf16 tin
            {
                float pc = 0.f, pcp = 0.f;
                #pragma unroll
                for (int r = 0; r < RPB; ++r) {
                    float a = xfer[r * 257 + tid];
                    float fv = fin[((size_t)(b * NF + f0 + r)) * ND + tid];
                    float qv = qpe[(size_t)(f0 + r) * ND + tid];
                    pc += a * fv;
                    pcp += a * (fv + qv);
                    int byte = (r * 512 + tid * 2) ^ ((r & 7) << 4);
                    *(short*)(tb + byte) = f2bf(a);
                }
                cpart [((size_t)tile * NB + b) * ND + tid] = pc;
                cppart[((size_t)tile * NB + b) * ND + tid] = pcp;
            }
            __syncthreads();

            // phase 6: alpha @ w_s^T -> xfer
            {
                f32x4 acc2[2][4];
                #pragma unroll
                for (int mt = 0; mt < 2; ++mt)
                    #pragma unroll
                    for (int nt = 0; nt < 4; ++nt)
                        acc2[mt][nt] = (f32x4)0.f;
                #pragma unroll
                for (int ks = 0; ks < 8; ++ks) {
                    int kb = ks * 32 + g * 8;
                    bf16x8 afr[2];
                    #pragma unroll
                    for (int mt = 0; mt < 2; ++mt) {
                        int row = mt * 16 + c15;
                        int byte = (row * 512 + kb * 2) ^ ((row & 7) << 4);
                        afr[mt] = *(const bf16x8*)(tb + byte);
                    }
                    #pragma unroll
                    for (int nt = 0; nt < 4; ++nt) {
                        int o = o0 + nt * 16 + c15;
                        bf16x8 bfr = *(const bf16x8*)(w_s_bf + (size_t)o * ND + kb);
                        #pragma unroll
                        for (int mt = 0; mt < 2; ++mt)
                            acc2[mt][nt] = __builtin_amdgcn_mfma_f32_16x16x32_bf16(afr[mt], bfr, acc2[mt][nt], 0, 0, 0);
                    }
                }
                #pragma unroll
                for (int mt = 0; mt < 2; ++mt)
                    #pragma unroll
                    for (int reg = 0; reg < 4; ++reg) {
                        int r = mt * 16 + g * 4 + reg;
                        #pragma unroll
                        for (int nt = 0; nt < 4; ++nt)
                            xfer[r * 257 + o0 + nt * 16 + c15] = acc2[mt][nt][reg];
                    }
            }
            __syncthreads();

            // phase 7: bsum += xfer (re-read bsum; L2-hot)
            #pragma unroll
            for (int r = 0; r < RPB; ++r) {
                size_t idx = ((size_t)(b * NF + f0 + r)) * ND + tid;
                bsum[idx] = bsum[idx] + xfer[r * 257 + tid];
            }
        }
        if (coop) grid.sync();
    }
}

extern "C" void kernel_launch(void* const* d_in, const int* in_sizes, int n_in,
                              void* d_out, int out_size, void* d_ws, size_t ws_size,
                              hipStream_t stream) {
    const float* fin  = (const float*)d_in[0];
    const int*   ids  = (const int*)  d_in[1];
    const float* emb  = (const float*)d_in[2];
    const float* w_e  = (const float*)d_in[3];
    const float* w_h  = (const float*)d_in[4];
    const float* w_f  = (const float*)d_in[5];
    const float* w_q  = (const float*)d_in[6];
    const float* w_s  = (const float*)d_in[7];
    const float* w_g  = (const float*)d_in[8];
    const float* w_ih = (const float*)d_in[9];
    const float* w_hh = (const float*)d_in[10];
    float* out = (float*)d_out;
    float* ws  = (float*)d_ws;

    size_t off = 0;
    float* q      = ws + off; off += (size_t)NF * ND;
    float* qwq    = ws + off; off += (size_t)NF * ND;
    float* bsum   = ws + off; off += (size_t)NB * NF * ND;
    float* h      = ws + off; off += (size_t)NB * ND;
    float* cell   = ws + off; off += (size_t)NB * ND;
    float* hwh    = ws + off; off += (size_t)NB * ND;
    float* ZT     = ws + off; off += (size_t)768 * NB;
    float* ZP     = ws + off; off += (size_t)NB * 512;
    float* cpart  = ws + off; off += (size_t)NTILE * NB * ND;
    float* cppart = ws + off; off += (size_t)NTILE * NB * ND;
    float* w_hT   = ws + off; off += (size_t)ND * ND;
    float* w_gT   = ws + off; off += (size_t)512 * ND;
    short* w_e_bf = (short*)(ws + off); off += (size_t)ND * ND / 2;
    short* w_s_bf = (short*)(ws + off); off += (size_t)ND * ND / 2;

    hipMemsetAsync(h, 0, sizeof(float) * NB * ND, stream);
    hipMemsetAsync(cell, 0, sizeof(float) * NB * ND, stream);

    pe_kernel<<<NF, ND, 0, stream>>>(q);
    wcvt_kernel<<<ND * ND / 256, 256, 0, stream>>>(w_e, w_e_bf, ND * ND);
    wcvt_kernel<<<ND * ND / 256, 256, 0, stream>>>(w_s, w_s_bf, ND * ND);
    wprep_kernel<<<512, ND, 0, stream>>>(w_h, w_g, w_hT, w_gT);
    qwq_kernel<<<NF, ND, 0, stream>>>(q, w_q, qwq);
    base_kernel<<<NB * NTILE, ND, 0, stream>>>(fin, w_f, qwq, bsum);

    int coop1 = 1, t00 = 0, smask15 = 15;
    void* args[] = {
        (void*)&coop1, (void*)&t00, (void*)&smask15,
        (void*)&fin, (void*)&ids, (void*)&emb, (void*)&q, (void*)&bsum,
        (void*)&w_ih, (void*)&w_hh, (void*)&w_hT, (void*)&w_gT,
        (void*)&w_e_bf, (void*)&w_s_bf,
        (void*)&h, (void*)&cell, (void*)&hwh,
        (void*)&ZT, (void*)&ZP, (void*)&cpart, (void*)&cppart, (void*)&out
    };
    hipError_t e = hipLaunchCooperativeKernel((void*)dec_step, dim3(NBLK), dim3(ND),
                                              args, 0, stream);
    if (e != hipSuccess) {
        // deterministic fallback: same kernel, per-stage launches (ordering via launch boundaries)
        for (int t = 0; t <= NT; ++t) {
            dec_step<<<NBLK, ND, 0, stream>>>(0, t, 1, fin, ids, emb, q, bsum, w_ih, w_hh,
                                              w_hT, w_gT, w_e_bf, w_s_bf, h, cell, hwh,
                                              ZT, ZP, cpart, cppart, out);
            if (t < NT)
                dec_step<<<NBLK, ND, 0, stream>>>(0, t, 2, fin, ids, emb, q, bsum, w_ih, w_hh,
                                                  w_hT, w_gT, w_e_bf, w_s_bf, h, cell, hwh,
                                                  ZT, ZP, cpart, cppart, out);
            dec_step<<<NBLK, ND, 0, stream>>>(0, t, 4, fin, ids, emb, q, bsum, w_ih, w_hh,
                                              w_hT, w_gT, w_e_bf, w_s_bf, h, cell, hwh,
                                              ZT, ZP, cpart, cppart, out);
            if (t < NT)
                dec_step<<<NBLK, ND, 0, stream>>>(0, t, 8, fin, ids, emb, q, bsum, w_ih, w_hh,
                                                  w_hT, w_gT, w_e_bf, w_s_bf, h, cell, hwh,
                                                  ZT, ZP, cpart, cppart, out);
        }
    }
}

// Round 12
// 15500.041 us; speedup vs baseline: 1.1935x; 1.1935x over previous
//
#include <hip/hip_runtime.h>
#include <math.h>

#define NB 32      // batch
#define NF 512     // feature_size
#define ND 256     // d_model
#define NT 32      // decode steps
#define RPB 32     // rows per attention tile
#define NTILE (NF / RPB)   // 16
#define NBLK (NB * NTILE)  // 512

typedef __attribute__((ext_vector_type(8))) short bf16x8;
typedef __attribute__((ext_vector_type(4))) float f32x4;

__device__ __forceinline__ float sigmoidf_(float x) { return 1.0f / (1.0f + __expf(-x)); }

__device__ __forceinline__ short f2bf(float x) {
    union { float f; unsigned u; } v; v.f = x;
    unsigned r = (v.u + 0x7FFF + ((v.u >> 16) & 1)) >> 16;
    return (short)r;
}

#define AGENT __HIP_MEMORY_SCOPE_AGENT
__device__ __forceinline__ float AL(const float* p) {
    return __hip_atomic_load(p, __ATOMIC_RELAXED, AGENT);
}
__device__ __forceinline__ void AS(float* p, float v) {
    __hip_atomic_store(p, v, __ATOMIC_RELAXED, AGENT);
}
__device__ __forceinline__ void wait_ge(int* p, int tgt, int tid) {
    if (tid == 0) {
        while (__hip_atomic_load(p, __ATOMIC_ACQUIRE, AGENT) < tgt)
            __builtin_amdgcn_s_sleep(2);
    }
    __syncthreads();
}

// ---------------- positional encoding q[F][D] ----------------
__global__ void pe_kernel(float* __restrict__ q) {
    int p = blockIdx.x;
    int d = threadIdx.x;
    float i2 = (float)((d >> 1) << 1);
    float rate = expf(-9.210340371976184f * (i2 / (float)ND));
    float ang = (float)p * rate;
    q[p * ND + d] = (d & 1) ? cosf(ang) : sinf(ang);
}

// ---------------- fp32 -> bf16 weight convert ----------------
__global__ void wcvt_kernel(const float* __restrict__ w, short* __restrict__ wb, int n) {
    int i = blockIdx.x * 256 + threadIdx.x;
    if (i < n) wb[i] = f2bf(w[i]);
}

// ---------------- weight prep: wcat[j][768] = [w_ih[j] | w_hh[j]]; w_hT; w_gT ----------------
__global__ void wprep_kernel(const float* __restrict__ w_ih, const float* __restrict__ w_hh,
                             const float* __restrict__ w_h, const float* __restrict__ w_g,
                             float* __restrict__ wcat, float* __restrict__ w_hT,
                             float* __restrict__ w_gT) {
    int j = blockIdx.x;      // 0..1023
    int o = threadIdx.x;     // 0..255
    wcat[(size_t)j * 768 + o]       = w_ih[(size_t)j * 512 + o];
    wcat[(size_t)j * 768 + 256 + o] = w_ih[(size_t)j * 512 + 256 + o];
    wcat[(size_t)j * 768 + 512 + o] = w_hh[(size_t)j * 256 + o];
    if (j < ND)  w_hT[(size_t)j * ND + o] = w_h[(size_t)o * ND + j];
    if (j < 512) w_gT[(size_t)j * ND + o] = w_g[(size_t)o * 512 + j];
}

// ---------------- qwq[p][o] = dot(q[p,:], w_q[o,:]) ----------------
__global__ void qwq_kernel(const float* __restrict__ q, const float* __restrict__ w_q,
                           float* __restrict__ qwq) {
    int p = blockIdx.x;
    int o = threadIdx.x;
    __shared__ float qs[ND];
    qs[o] = q[(size_t)p * ND + o];
    __syncthreads();
    const float4* wr = (const float4*)(w_q + (size_t)o * ND);
    float acc = 0.f;
    for (int k4 = 0; k4 < ND / 4; ++k4) {
        float4 w = wr[k4];
        int k = 4 * k4;
        acc += qs[k] * w.x + qs[k + 1] * w.y + qs[k + 2] * w.z + qs[k + 3] * w.w;
    }
    qwq[(size_t)p * ND + o] = acc;
}

// ---------------- bsum = f@w_f^T + qwq ----------------
__global__ void base_kernel(const float* __restrict__ fin, const float* __restrict__ w_f,
                            const float* __restrict__ qwq, float* __restrict__ bsum) {
    int b = blockIdx.x / NTILE;
    int f0 = (blockIdx.x % NTILE) * RPB;
    int o = threadIdx.x;
    __shared__ float fs[RPB][ND];
    #pragma unroll
    for (int r = 0; r < RPB; ++r)
        fs[r][o] = fin[((size_t)(b * NF + f0 + r)) * ND + o];
    __syncthreads();
    float acc[RPB];
    #pragma unroll
    for (int r = 0; r < RPB; ++r) acc[r] = 0.f;
    const float4* wr = (const float4*)(w_f + (size_t)o * ND);
    for (int k4 = 0; k4 < ND / 4; ++k4) {
        float4 w = wr[k4];
        int k = 4 * k4;
        #pragma unroll
        for (int r = 0; r < RPB; ++r)
            acc[r] += fs[r][k] * w.x + fs[r][k + 1] * w.y + fs[r][k + 2] * w.z + fs[r][k + 3] * w.w;
    }
    #pragma unroll
    for (int r = 0; r < RPB; ++r)
        bsum[((size_t)(b * NF + f0 + r)) * ND + o] = acc[r] + qwq[(size_t)(f0 + r) * ND + o];
}

// ---------------- persistent decoder: per-batch flag pipeline, NO grid.sync ----------------
// Per step t, block (b,tile):
//   GATES: wait acount[b]>=16t, hflag[b]>=t; build Z; compute 64 gate rows -> gatesT; gcount[b]++
//   PW (tile0): wait gcount[b]>=16(t+1); LSTM pointwise -> h[(t+1)&1]; hflag[b]=t+1
//   PRED (tile1, t>0): csum + pred -> out[t-1]   (inputs gated by the gates-stage wait)
//   A: wait hflag[b]>=t+1; hwh (local); attn phases 1-7; cpart/cppart[t&1]; acount[b]++
__global__ void __launch_bounds__(256, 2) dec_persist(
        int coop, int t0, int smask,
        const float* __restrict__ fin, const int* __restrict__ ids,
        const float* __restrict__ emb, const float* __restrict__ qpe,
        float* __restrict__ bsum,
        const float* __restrict__ wcat, const float* __restrict__ w_hT,
        const float* __restrict__ w_gT,
        const short* __restrict__ w_e_bf, const short* __restrict__ w_s_bf,
        float* __restrict__ h, float* __restrict__ cell,
        float* __restrict__ gatesT,
        float* __restrict__ cpart, float* __restrict__ cppart,
        int* __restrict__ acount, int* __restrict__ gcount, int* __restrict__ hflag,
        float* __restrict__ out) {
    int bid = blockIdx.x;
    int tid = threadIdx.x;
    int l = tid & 63;
    int wv = tid >> 6;
    int c15 = l & 15;
    int g = l >> 4;

    int b = bid >> 4;
    int tile = bid & 15;
    int f0 = tile * RPB;
    int o0 = wv * 64;

    __shared__ __align__(16) short tin_bf[RPB * ND];   // 16 KB
    __shared__ float xfer[RPB * 257];                  // 32.9 KB (aliased: zl / zp / hn)
    __shared__ float sred[RPB][5];
    char* tb = (char*)tin_bf;
    float* zl = xfer;    // [768]
    float* zp = xfer;    // [512]
    float* hn = xfer;    // [256]

    const size_t CP = (size_t)NTILE * NB * ND;   // parity stride for cpart/cppart

    int tbeg = coop ? 0 : t0;
    int tend = coop ? NT : t0;

    for (int t = tbeg; t <= tend; ++t) {
        int prd = (t > 0) ? ((t - 1) & 1) : 0;

        // ===== GATES =====
        if ((smask & 1) && t < NT) {
            if (coop) {
                if (tid == 0) {
                    while (__hip_atomic_load(&acount[b], __ATOMIC_ACQUIRE, AGENT) < 16 * t)
                        __builtin_amdgcn_s_sleep(2);
                    while (__hip_atomic_load(&hflag[b], __ATOMIC_ACQUIRE, AGENT) < t)
                        __builtin_amdgcn_s_sleep(2);
                }
                __syncthreads();
            }
            float xv = emb[(size_t)ids[b * NT + t] * ND + tid];
            float cpsum = 0.f;
            if (t > 0) {
                #pragma unroll
                for (int tl = 0; tl < NTILE; ++tl)
                    cpsum += AL(&cppart[prd * CP + ((size_t)tl * NB + b) * ND + tid]);
            }
            zl[tid] = xv;
            zl[256 + tid] = cpsum;
            zl[512 + tid] = AL(&h[(size_t)(t & 1) * NB * ND + b * ND + tid]);
            __syncthreads();
            int j0 = tile * 64 + wv * 16;
            for (int jj = 0; jj < 16; ++jj) {
                int j = j0 + jj;
                const float* wr = wcat + (size_t)j * 768;
                float s = 0.f;
                #pragma unroll
                for (int i = 0; i < 12; ++i)
                    s += wr[l + i * 64] * zl[l + i * 64];
                #pragma unroll
                for (int off = 1; off <= 32; off <<= 1)
                    s += __shfl_xor(s, off);
                if (l == 0) AS(&gatesT[(size_t)b * 1024 + j], s);
            }
            __syncthreads();
            if (coop && tid == 0)
                __hip_atomic_fetch_add(&gcount[b], 1, __ATOMIC_RELEASE, AGENT);
        }

        // ===== POINTWISE (tile 0) =====
        if ((smask & 2) && t < NT && tile == 0) {
            if (coop) wait_ge(&gcount[b], 16 * (t + 1), tid);
            float gi = AL(&gatesT[(size_t)b * 1024 + tid]);
            float gf = AL(&gatesT[(size_t)b * 1024 + 256 + tid]);
            float gg = AL(&gatesT[(size_t)b * 1024 + 512 + tid]);
            float go = AL(&gatesT[(size_t)b * 1024 + 768 + tid]);
            float cold = cell[(size_t)b * ND + tid];
            float cnew = sigmoidf_(gf) * cold + sigmoidf_(gi) * tanhf(gg);
            float hval = sigmoidf_(go) * tanhf(cnew);
            cell[(size_t)b * ND + tid] = cnew;
            AS(&h[(size_t)((t + 1) & 1) * NB * ND + b * ND + tid], hval);
            __syncthreads();
            if (coop && tid == 0)
                __hip_atomic_store(&hflag[b], t + 1, __ATOMIC_RELEASE, AGENT);
        }

        // ===== PRED (tile 1, t>0) =====
        if ((smask & 2) && t > 0 && tile == 1) {
            if (coop && t == NT) {   // gates stage skipped this iteration: gate inputs here
                if (tid == 0) {
                    while (__hip_atomic_load(&acount[b], __ATOMIC_ACQUIRE, AGENT) < 16 * t)
                        __builtin_amdgcn_s_sleep(2);
                    while (__hip_atomic_load(&hflag[b], __ATOMIC_ACQUIRE, AGENT) < t)
                        __builtin_amdgcn_s_sleep(2);
                }
                __syncthreads();
            }
            float csum = 0.f;
            #pragma unroll
            for (int tl = 0; tl < NTILE; ++tl)
                csum += AL(&cpart[prd * CP + ((size_t)tl * NB + b) * ND + tid]);
            zp[tid] = csum;
            zp[256 + tid] = AL(&h[(size_t)(t & 1) * NB * ND + b * ND + tid]);
            __syncthreads();
            float p = 0.f;
            #pragma unroll 8
            for (int k = 0; k < 512; ++k)
                p += zp[k] * w_gT[(size_t)k * ND + tid];
            out[((size_t)b * NT + (t - 1)) * ND + tid] = p;
            __syncthreads();
        }

        if (t >= NT) continue;

        // ===== A (attention) =====
        if (smask & 4) {
            if (coop) wait_ge(&hflag[b], t + 1, tid);
            hn[tid] = AL(&h[(size_t)((t + 1) & 1) * NB * ND + b * ND + tid]);
            __syncthreads();
            float hwh_reg = 0.f;
            #pragma unroll 8
            for (int k = 0; k < ND; ++k)
                hwh_reg += hn[k] * w_hT[(size_t)k * ND + tid];
            __syncthreads();

            // phase 1: tin = tanh(hwh + bsum) -> bf16 swizzled LDS (bsum plain: block-affine)
            #pragma unroll
            for (int r = 0; r < RPB; ++r) {
                float bs = bsum[((size_t)(b * NF + f0 + r)) * ND + tid];
                int byte = (r * 512 + tid * 2) ^ ((r & 7) << 4);
                *(short*)(tb + byte) = f2bf(tanhf(hwh_reg + bs));
            }
            __syncthreads();

            // phase 2: e = tin @ w_e^T
            f32x4 acc[2][4];
            #pragma unroll
            for (int mt = 0; mt < 2; ++mt)
                #pragma unroll
                for (int nt = 0; nt < 4; ++nt)
                    acc[mt][nt] = (f32x4)0.f;
            #pragma unroll
            for (int ks = 0; ks < 8; ++ks) {
                int kb = ks * 32 + g * 8;
                bf16x8 afr[2];
                #pragma unroll
                for (int mt = 0; mt < 2; ++mt) {
                    int row = mt * 16 + c15;
                    int byte = (row * 512 + kb * 2) ^ ((row & 7) << 4);
                    afr[mt] = *(const bf16x8*)(tb + byte);
                }
                #pragma unroll
                for (int nt = 0; nt < 4; ++nt) {
                    int o = o0 + nt * 16 + c15;
                    bf16x8 bfr = *(const bf16x8*)(w_e_bf + (size_t)o * ND + kb);
                    #pragma unroll
                    for (int mt = 0; mt < 2; ++mt)
                        acc[mt][nt] = __builtin_amdgcn_mfma_f32_16x16x32_bf16(afr[mt], bfr, acc[mt][nt], 0, 0, 0);
                }
            }

            // phase 3: in-register softmax over cols
            {
                float ps[2][4];
                #pragma unroll
                for (int mt = 0; mt < 2; ++mt)
                    #pragma unroll
                    for (int reg = 0; reg < 4; ++reg) ps[mt][reg] = 0.f;
                #pragma unroll
                for (int mt = 0; mt < 2; ++mt)
                    #pragma unroll
                    for (int nt = 0; nt < 4; ++nt)
                        #pragma unroll
                        for (int reg = 0; reg < 4; ++reg) {
                            float a = __expf(acc[mt][nt][reg]);
                            acc[mt][nt][reg] = a;
                            ps[mt][reg] += a;
                        }
                #pragma unroll
                for (int off = 1; off <= 8; off <<= 1)
                    #pragma unroll
                    for (int mt = 0; mt < 2; ++mt)
                        #pragma unroll
                        for (int reg = 0; reg < 4; ++reg)
                            ps[mt][reg] += __shfl_xor(ps[mt][reg], off);
                if (c15 == 0) {
                    #pragma unroll
                    for (int mt = 0; mt < 2; ++mt)
                        #pragma unroll
                        for (int reg = 0; reg < 4; ++reg)
                            sred[mt * 16 + g * 4 + reg][wv] = ps[mt][reg];
                }
                __syncthreads();
                #pragma unroll
                for (int mt = 0; mt < 2; ++mt)
                    #pragma unroll
                    for (int reg = 0; reg < 4; ++reg) {
                        int r = mt * 16 + g * 4 + reg;
                        float inv = 1.0f / (sred[r][0] + sred[r][1] + sred[r][2] + sred[r][3]);
                        #pragma unroll
                        for (int nt = 0; nt < 4; ++nt)
                            acc[mt][nt][reg] *= inv;
                    }
            }

            // phase 4: alpha C-layout -> xfer
            #pragma unroll
            for (int mt = 0; mt < 2; ++mt)
                #pragma unroll
                for (int reg = 0; reg < 4; ++reg) {
                    int r = mt * 16 + g * 4 + reg;
                    #pragma unroll
                    for (int nt = 0; nt < 4; ++nt)
                        xfer[r * 257 + o0 + nt * 16 + c15] = acc[mt][nt][reg];
                }
            __syncthreads();

            // phase 5: c/cp partials col-parallel; alpha -> bf16 tin
            {
                float pc = 0.f, pcp = 0.f;
                #pragma unroll
                for (int r = 0; r < RPB; ++r) {
                    float a = xfer[r * 257 + tid];
                    float fv = fin[((size_t)(b * NF + f0 + r)) * ND + tid];
                    float qv = qpe[(size_t)(f0 + r) * ND + tid];
                    pc += a * fv;
                    pcp += a * (fv + qv);
                    int byte = (r * 512 + tid * 2) ^ ((r & 7) << 4);
                    *(short*)(tb + byte) = f2bf(a);
                }
                AS(&cpart [(size_t)(t & 1) * CP + ((size_t)tile * NB + b) * ND + tid], pc);
                AS(&cppart[(size_t)(t & 1) * CP + ((size_t)tile * NB + b) * ND + tid], pcp);
            }
            __syncthreads();

            // phase 6: alpha @ w_s^T -> xfer
            {
                f32x4 acc2[2][4];
                #pragma unroll
                for (int mt = 0; mt < 2; ++mt)
                    #pragma unroll
                    for (int nt = 0; nt < 4; ++nt)
                        acc2[mt][nt] = (f32x4)0.f;
                #pragma unroll
                for (int ks = 0; ks < 8; ++ks) {
                    int kb = ks * 32 + g * 8;
                    bf16x8 afr[2];
                    #pragma unroll
                    for (int mt = 0; mt < 2; ++mt) {
                        int row = mt * 16 + c15;
                        int byte = (row * 512 + kb * 2) ^ ((row & 7) << 4);
                        afr[mt] = *(const bf16x8*)(tb + byte);
                    }
                    #pragma unroll
                    for (int nt = 0; nt < 4; ++nt) {
                        int o = o0 + nt * 16 + c15;
                        bf16x8 bfr = *(const bf16x8*)(w_s_bf + (size_t)o * ND + kb);
                        #pragma unroll
                        for (int mt = 0; mt < 2; ++mt)
                            acc2[mt][nt] = __builtin_amdgcn_mfma_f32_16x16x32_bf16(afr[mt], bfr, acc2[mt][nt], 0, 0, 0);
                    }
                }
                #pragma unroll
                for (int mt = 0; mt < 2; ++mt)
                    #pragma unroll
                    for (int reg = 0; reg < 4; ++reg) {
                        int r = mt * 16 + g * 4 + reg;
                        #pragma unroll
                        for (int nt = 0; nt < 4; ++nt)
                            xfer[r * 257 + o0 + nt * 16 + c15] = acc2[mt][nt][reg];
                    }
            }
            __syncthreads();

            // phase 7: bsum += xfer (plain, block-affine)
            #pragma unroll
            for (int r = 0; r < RPB; ++r) {
                size_t idx = ((size_t)(b * NF + f0 + r)) * ND + tid;
                bsum[idx] = bsum[idx] + xfer[r * 257 + tid];
            }
            __syncthreads();
            if (coop && tid == 0)
                __hip_atomic_fetch_add(&acount[b], 1, __ATOMIC_RELEASE, AGENT);
        }
    }
}

extern "C" void kernel_launch(void* const* d_in, const int* in_sizes, int n_in,
                              void* d_out, int out_size, void* d_ws, size_t ws_size,
                              hipStream_t stream) {
    const float* fin  = (const float*)d_in[0];
    const int*   ids  = (const int*)  d_in[1];
    const float* emb  = (const float*)d_in[2];
    const float* w_e  = (const float*)d_in[3];
    const float* w_h  = (const float*)d_in[4];
    const float* w_f  = (const float*)d_in[5];
    const float* w_q  = (const float*)d_in[6];
    const float* w_s  = (const float*)d_in[7];
    const float* w_g  = (const float*)d_in[8];
    const float* w_ih = (const float*)d_in[9];
    const float* w_hh = (const float*)d_in[10];
    float* out = (float*)d_out;
    float* ws  = (float*)d_ws;

    size_t off = 0;
    float* q      = ws + off; off += (size_t)NF * ND;
    float* qwq    = ws + off; off += (size_t)NF * ND;
    float* bsum   = ws + off; off += (size_t)NB * NF * ND;
    float* h      = ws + off; off += (size_t)2 * NB * ND;
    float* cell   = ws + off; off += (size_t)NB * ND;
    float* gatesT = ws + off; off += (size_t)NB * 1024;
    float* cpart  = ws + off; off += (size_t)2 * NTILE * NB * ND;
    float* cppart = ws + off; off += (size_t)2 * NTILE * NB * ND;
    float* wcat   = ws + off; off += (size_t)1024 * 768;
    float* w_hT   = ws + off; off += (size_t)ND * ND;
    float* w_gT   = ws + off; off += (size_t)512 * ND;
    short* w_e_bf = (short*)(ws + off); off += (size_t)ND * ND / 2;
    short* w_s_bf = (short*)(ws + off); off += (size_t)ND * ND / 2;
    int*   acount = (int*)(ws + off); off += 32;
    int*   gcount = (int*)(ws + off); off += 32;
    int*   hflag  = (int*)(ws + off); off += 32;

    hipMemsetAsync(h, 0, sizeof(float) * NB * ND, stream);            // h[0] only
    hipMemsetAsync(cell, 0, sizeof(float) * NB * ND, stream);
    hipMemsetAsync(acount, 0, sizeof(int) * 96, stream);              // acount,gcount,hflag

    pe_kernel<<<NF, ND, 0, stream>>>(q);
    wcvt_kernel<<<ND * ND / 256, 256, 0, stream>>>(w_e, w_e_bf, ND * ND);
    wcvt_kernel<<<ND * ND / 256, 256, 0, stream>>>(w_s, w_s_bf, ND * ND);
    wprep_kernel<<<1024, ND, 0, stream>>>(w_ih, w_hh, w_h, w_g, wcat, w_hT, w_gT);
    qwq_kernel<<<NF, ND, 0, stream>>>(q, w_q, qwq);
    base_kernel<<<NB * NTILE, ND, 0, stream>>>(fin, w_f, qwq, bsum);

    int coop1 = 1, t00 = 0, smask7 = 7;
    void* args[] = {
        (void*)&coop1, (void*)&t00, (void*)&smask7,
        (void*)&fin, (void*)&ids, (void*)&emb, (void*)&q, (void*)&bsum,
        (void*)&wcat, (void*)&w_hT, (void*)&w_gT,
        (void*)&w_e_bf, (void*)&w_s_bf,
        (void*)&h, (void*)&cell, (void*)&gatesT,
        (void*)&cpart, (void*)&cppart,
        (void*)&acount, (void*)&gcount, (void*)&hflag,
        (void*)&out
    };
    hipError_t e = hipLaunchCooperativeKernel((void*)dec_persist, dim3(NBLK), dim3(ND),
                                              args, 0, stream);
    if (e != hipSuccess) {
        // fallback: per-stage launches, flags unused (coop=0), ordering via boundaries
        for (int t = 0; t <= NT; ++t) {
            if (t < NT)
                dec_persist<<<NBLK, ND, 0, stream>>>(0, t, 1, fin, ids, emb, q, bsum,
                        wcat, w_hT, w_gT, w_e_bf, w_s_bf, h, cell, gatesT,
                        cpart, cppart, acount, gcount, hflag, out);
            dec_persist<<<NBLK, ND, 0, stream>>>(0, t, 2, fin, ids, emb, q, bsum,
                    wcat, w_hT, w_gT, w_e_bf, w_s_bf, h, cell, gatesT,
                    cpart, cppart, acount, gcount, hflag, out);
            if (t < NT)
                dec_persist<<<NBLK, ND, 0, stream>>>(0, t, 4, fin, ids, emb, q, bsum,
                        wcat, w_hT, w_gT, w_e_bf, w_s_bf, h, cell, gatesT,
                        cpart, cppart, acount, gcount, hflag, out);
        }
    }
}

// Round 13
// 2679.944 us; speedup vs baseline: 6.9030x; 5.7837x over previous
//
#include <hip/hip_runtime.h>
#include <math.h>

#define NB 32      // batch
#define NF 512     // feature_size
#define ND 256     // d_model
#define NT 32      // decode steps
#define RPB 32     // rows per attention tile
#define NTILE (NF / RPB)   // 16
#define XS 260     // xfer stride (floats), float4-aligned

typedef __attribute__((ext_vector_type(8))) short bf16x8;
typedef __attribute__((ext_vector_type(4))) short bf16x4;
typedef __attribute__((ext_vector_type(4))) float f32x4;

__device__ __forceinline__ float sigmoidf_(float x) { return 1.0f / (1.0f + __expf(-x)); }

__device__ __forceinline__ short f2bf(float x) {
    union { float f; unsigned u; } v; v.f = x;
    unsigned r = (v.u + 0x7FFF + ((v.u >> 16) & 1)) >> 16;
    return (short)r;
}

// ---------------- positional encoding q[F][D] ----------------
__global__ void pe_kernel(float* __restrict__ q) {
    int p = blockIdx.x;
    int d = threadIdx.x;
    float i2 = (float)((d >> 1) << 1);
    float rate = expf(-9.210340371976184f * (i2 / (float)ND));
    float ang = (float)p * rate;
    q[p * ND + d] = (d & 1) ? cosf(ang) : sinf(ang);
}

// ---------------- fp32 -> bf16 weight convert ----------------
__global__ void wcvt_kernel(const float* __restrict__ w, short* __restrict__ wb, int n) {
    int i = blockIdx.x * 256 + threadIdx.x;
    if (i < n) wb[i] = f2bf(w[i]);
}

// ---------------- transposes: w_hT[k][o], w_gT[k][o] ----------------
__global__ void wprep_kernel(const float* __restrict__ w_h, const float* __restrict__ w_g,
                             float* __restrict__ w_hT, float* __restrict__ w_gT) {
    int k = blockIdx.x;      // 0..511
    int o = threadIdx.x;
    if (k < ND) w_hT[(size_t)k * ND + o] = w_h[(size_t)o * ND + k];
    w_gT[(size_t)k * ND + o] = w_g[(size_t)o * 512 + k];
}

// ---------------- qwq[p][o] = dot(q[p,:], w_q[o,:]) ----------------
__global__ void qwq_kernel(const float* __restrict__ q, const float* __restrict__ w_q,
                           float* __restrict__ qwq) {
    int p = blockIdx.x;
    int o = threadIdx.x;
    __shared__ float qs[ND];
    qs[o] = q[(size_t)p * ND + o];
    __syncthreads();
    const float4* wr = (const float4*)(w_q + (size_t)o * ND);
    float acc = 0.f;
    for (int k4 = 0; k4 < ND / 4; ++k4) {
        float4 w = wr[k4];
        int k = 4 * k4;
        acc += qs[k] * w.x + qs[k + 1] * w.y + qs[k + 2] * w.z + qs[k + 3] * w.w;
    }
    qwq[(size_t)p * ND + o] = acc;
}

// ---------------- bsum = f@w_f^T + qwq ----------------
__global__ void base_kernel(const float* __restrict__ fin, const float* __restrict__ w_f,
                            const float* __restrict__ qwq, float* __restrict__ bsum) {
    int b = blockIdx.x / NTILE;
    int f0 = (blockIdx.x % NTILE) * RPB;
    int o = threadIdx.x;
    __shared__ float fs[RPB][ND];
    #pragma unroll
    for (int r = 0; r < RPB; ++r)
        fs[r][o] = fin[((size_t)(b * NF + f0 + r)) * ND + o];
    __syncthreads();
    float acc[RPB];
    #pragma unroll
    for (int r = 0; r < RPB; ++r) acc[r] = 0.f;
    const float4* wr = (const float4*)(w_f + (size_t)o * ND);
    for (int k4 = 0; k4 < ND / 4; ++k4) {
        float4 w = wr[k4];
        int k = 4 * k4;
        #pragma unroll
        for (int r = 0; r < RPB; ++r)
            acc[r] += fs[r][k] * w.x + fs[r][k + 1] * w.y + fs[r][k + 2] * w.z + fs[r][k + 3] * w.w;
    }
    #pragma unroll
    for (int r = 0; r < RPB; ++r)
        bsum[((size_t)(b * NF + f0 + r)) * ND + o] = acc[r] + qwq[(size_t)(f0 + r) * ND + o];
}

// ---------------- gates + pred ----------------
// blocks 0..127: 8 gate rows each, Z staged in LDS. blocks 128..159: pred for batch (bid-128).
#define ZSTRIDE 769
__global__ void gates_kernel(int t, int mode,
                             const int* __restrict__ ids, const float* __restrict__ emb,
                             const float* __restrict__ cpart, const float* __restrict__ cppart,
                             const float* __restrict__ h,
                             const float* __restrict__ w_ih, const float* __restrict__ w_hh,
                             const float* __restrict__ w_gT,
                             float* __restrict__ gatesT, float* __restrict__ out) {
    extern __shared__ float lds[];
    int bid = blockIdx.x;
    int tid = threadIdx.x;

    if (bid < 128) {
        if (!(mode & 1)) return;
        int j0 = bid * 8;
        float* wl = lds;              // [8][768]
        float* zl = lds + 8 * 768;    // [32][ZSTRIDE]
        float4* wl4 = (float4*)wl;
        for (int cc = 0; cc < 6; ++cc) {
            int idx4 = tid + cc * 256;
            int flat = idx4 * 4;
            int r = flat / 768;
            int col = flat - r * 768;
            float4 v;
            if (col < 512) v = *(const float4*)(w_ih + (size_t)(j0 + r) * 512 + col);
            else           v = *(const float4*)(w_hh + (size_t)(j0 + r) * 256 + (col - 512));
            wl4[idx4] = v;
        }
        // Z[b] = [x_t | cpsum | h]
        for (int b = 0; b < NB; ++b) {
            int d = tid;
            float xv = (t < NT) ? emb[(size_t)ids[b * NT + t] * ND + d] : 0.f;
            float cpsum = 0.f;
            if (t > 0) {
                #pragma unroll
                for (int tl = 0; tl < NTILE; ++tl)
                    cpsum += cppart[((size_t)tl * NB + b) * ND + d];
            }
            float hv = h[(size_t)b * ND + d];
            zl[b * ZSTRIDE + d]       = xv;
            zl[b * ZSTRIDE + 256 + d] = cpsum;
            zl[b * ZSTRIDE + 512 + d] = hv;
        }
        __syncthreads();
        int r = tid >> 5;
        int b = tid & 31;
        const float4* wr4 = (const float4*)(wl + r * 768);
        const float* zb = zl + b * ZSTRIDE;
        float acc = 0.f;
        #pragma unroll 8
        for (int k4 = 0; k4 < 192; ++k4) {
            float4 w = wr4[k4];
            int k = 4 * k4;
            acc += w.x * zb[k] + w.y * zb[k + 1] + w.z * zb[k + 2] + w.w * zb[k + 3];
        }
        gatesT[(size_t)b * 1024 + (j0 + r)] = acc;
    } else {
        if (!(mode & 2)) return;
        int b = bid - 128;
        float* zp = lds;              // [512]
        float csum = 0.f;
        #pragma unroll
        for (int tl = 0; tl < NTILE; ++tl)
            csum += cpart[((size_t)tl * NB + b) * ND + tid];
        zp[tid] = csum;
        zp[256 + tid] = h[(size_t)b * ND + tid];
        __syncthreads();
        float p = 0.f;
        #pragma unroll 8
        for (int k = 0; k < 512; ++k)
            p += zp[k] * w_gT[(size_t)k * ND + tid];
        out[((size_t)b * NT + (t - 1)) * ND + tid] = p;
    }
}

// ---------------- fused attention step: LSTM pointwise + hwh + MFMA attn, float4 streams ----------------
// C-fragment mapping: row = mt*16 + (l>>4)*4 + reg ; col = wv*64 + nt*16 + (l&15).
// tin_bf swizzle: element (r,k) at byte (r*512 + k*2) ^ ((r&7)<<4); 8B groups preserve it.
// float4 thread mapping for phases 1/5/7: wave wv owns rows {wv+4i}, lane c=tid&63 owns cols 4c..4c+3.
__global__ void __launch_bounds__(256, 2) attn_step_kernel(
        float* __restrict__ bsum,
        const float* __restrict__ fin, const float* __restrict__ qpe,
        const float* __restrict__ gatesT,
        const float* __restrict__ cell_prev, float* __restrict__ cell_next,
        float* __restrict__ h_next,
        const float* __restrict__ w_hT,
        const short* __restrict__ w_e_bf, const short* __restrict__ w_s_bf,
        float* __restrict__ cpart, float* __restrict__ cppart) {
    int b = blockIdx.x / NTILE;
    int tile = blockIdx.x % NTILE;
    int f0 = tile * RPB;
    int tid = threadIdx.x;
    int l = tid & 63;
    int wv = tid >> 6;
    int c15 = l & 15;
    int g = l >> 4;
    int c = l;               // float4 col group
    int o0 = wv * 64;

    __shared__ __align__(16) short tin_bf[RPB * ND];   // 16 KB
    __shared__ float xfer[RPB * XS];                   // 33.3 KB (aliased hn/hwhl in phase 0)
    __shared__ float cred[2][1024];                    // 8 KB cross-wave c/cp partials
    __shared__ float sred[RPB][5];
    char* tb = (char*)tin_bf;
    float* hn = xfer;            // [256]
    float* hwhl = xfer + 256;    // [256]

    // ---- phase 0: LSTM pointwise + hwh GEMV (w_hT coalesced) ----
    {
        float gi = gatesT[(size_t)b * 1024 + tid];
        float gf = gatesT[(size_t)b * 1024 + 256 + tid];
        float gg = gatesT[(size_t)b * 1024 + 512 + tid];
        float go = gatesT[(size_t)b * 1024 + 768 + tid];
        float cold = cell_prev[(size_t)b * ND + tid];
        float cnew = sigmoidf_(gf) * cold + sigmoidf_(gi) * tanhf(gg);
        float hval = sigmoidf_(go) * tanhf(cnew);
        if (tile == 0) {
            cell_next[(size_t)b * ND + tid] = cnew;
            h_next[(size_t)b * ND + tid] = hval;
        }
        hn[tid] = hval;
    }
    __syncthreads();
    {
        float a = 0.f;
        #pragma unroll 8
        for (int k = 0; k < ND; ++k)
            a += hn[k] * w_hT[(size_t)k * ND + tid];
        hwhl[tid] = a;
    }
    __syncthreads();

    // ---- phase 1: bsv4 regs; tin = tanh(hwh + bsum) -> bf16 swizzled (float4 loads) ----
    float4 bsv4[8];
    {
        float4 hwh4 = *(const float4*)&hwhl[4 * c];
        #pragma unroll
        for (int i = 0; i < 8; ++i) {
            int r = wv + 4 * i;
            bsv4[i] = *(const float4*)(bsum + ((size_t)(b * NF + f0 + r)) * ND + 4 * c);
            bf16x4 tv;
            tv.x = f2bf(tanhf(hwh4.x + bsv4[i].x));
            tv.y = f2bf(tanhf(hwh4.y + bsv4[i].y));
            tv.z = f2bf(tanhf(hwh4.z + bsv4[i].z));
            tv.w = f2bf(tanhf(hwh4.w + bsv4[i].w));
            *(bf16x4*)(tb + ((r * 512 + 8 * c) ^ ((r & 7) << 4))) = tv;
        }
    }
    __syncthreads();

    // ---- phase 2: e = tin @ w_e^T via MFMA ----
    f32x4 acc[2][4];
    #pragma unroll
    for (int mt = 0; mt < 2; ++mt)
        #pragma unroll
        for (int nt = 0; nt < 4; ++nt)
            acc[mt][nt] = (f32x4)0.f;
    #pragma unroll
    for (int ks = 0; ks < 8; ++ks) {
        int kb = ks * 32 + g * 8;
        bf16x8 afr[2];
        #pragma unroll
        for (int mt = 0; mt < 2; ++mt) {
            int row = mt * 16 + c15;
            afr[mt] = *(const bf16x8*)(tb + ((row * 512 + kb * 2) ^ ((row & 7) << 4)));
        }
        #pragma unroll
        for (int nt = 0; nt < 4; ++nt) {
            int o = o0 + nt * 16 + c15;
            bf16x8 bfr = *(const bf16x8*)(w_e_bf + (size_t)o * ND + kb);
            #pragma unroll
            for (int mt = 0; mt < 2; ++mt)
                acc[mt][nt] = __builtin_amdgcn_mfma_f32_16x16x32_bf16(afr[mt], bfr, acc[mt][nt], 0, 0, 0);
        }
    }

    // ---- phase 3: in-register softmax over cols ----
    {
        float ps[2][4];
        #pragma unroll
        for (int mt = 0; mt < 2; ++mt)
            #pragma unroll
            for (int reg = 0; reg < 4; ++reg) ps[mt][reg] = 0.f;
        #pragma unroll
        for (int mt = 0; mt < 2; ++mt)
            #pragma unroll
            for (int nt = 0; nt < 4; ++nt)
                #pragma unroll
                for (int reg = 0; reg < 4; ++reg) {
                    float a = __expf(acc[mt][nt][reg]);
                    acc[mt][nt][reg] = a;
                    ps[mt][reg] += a;
                }
        #pragma unroll
        for (int off = 1; off <= 8; off <<= 1)
            #pragma unroll
            for (int mt = 0; mt < 2; ++mt)
                #pragma unroll
                for (int reg = 0; reg < 4; ++reg)
                    ps[mt][reg] += __shfl_xor(ps[mt][reg], off);
        if (c15 == 0) {
            #pragma unroll
            for (int mt = 0; mt < 2; ++mt)
                #pragma unroll
                for (int reg = 0; reg < 4; ++reg)
                    sred[mt * 16 + g * 4 + reg][wv] = ps[mt][reg];
        }
        __syncthreads();
        #pragma unroll
        for (int mt = 0; mt < 2; ++mt)
            #pragma unroll
            for (int reg = 0; reg < 4; ++reg) {
                int r = mt * 16 + g * 4 + reg;
                float inv = 1.0f / (sred[r][0] + sred[r][1] + sred[r][2] + sred[r][3]);
                #pragma unroll
                for (int nt = 0; nt < 4; ++nt)
                    acc[mt][nt][reg] *= inv;
            }
    }

    // ---- phase 4: alpha C-layout -> xfer ----
    #pragma unroll
    for (int mt = 0; mt < 2; ++mt)
        #pragma unroll
        for (int reg = 0; reg < 4; ++reg) {
            int r = mt * 16 + g * 4 + reg;
            #pragma unroll
            for (int nt = 0; nt < 4; ++nt)
                xfer[r * XS + o0 + nt * 16 + c15] = acc[mt][nt][reg];
        }
    __syncthreads();

    // ---- phase 5a: c/cp partials (float4 fin/q); alpha -> bf16 tin ----
    {
        float4 pc4 = {0.f, 0.f, 0.f, 0.f}, pcp4 = {0.f, 0.f, 0.f, 0.f};
        #pragma unroll
        for (int i = 0; i < 8; ++i) {
            int r = wv + 4 * i;
            float4 a4 = *(const float4*)&xfer[r * XS + 4 * c];
            float4 f4 = *(const float4*)(fin + ((size_t)(b * NF + f0 + r)) * ND + 4 * c);
            float4 q4 = *(const float4*)(qpe + ((size_t)(f0 + r)) * ND + 4 * c);
            pc4.x += a4.x * f4.x;  pcp4.x += a4.x * (f4.x + q4.x);
            pc4.y += a4.y * f4.y;  pcp4.y += a4.y * (f4.y + q4.y);
            pc4.z += a4.z * f4.z;  pcp4.z += a4.z * (f4.z + q4.z);
            pc4.w += a4.w * f4.w;  pcp4.w += a4.w * (f4.w + q4.w);
            bf16x4 av;
            av.x = f2bf(a4.x); av.y = f2bf(a4.y); av.z = f2bf(a4.z); av.w = f2bf(a4.w);
            *(bf16x4*)(tb + ((r * 512 + 8 * c) ^ ((r & 7) << 4))) = av;
        }
        *(float4*)&cred[0][wv * 256 + 4 * c] = pc4;
        *(float4*)&cred[1][wv * 256 + 4 * c] = pcp4;
    }
    __syncthreads();

    // ---- phase 5b: finalize c/cp (coalesced store) ----
    {
        float pc  = cred[0][tid] + cred[0][256 + tid] + cred[0][512 + tid] + cred[0][768 + tid];
        float pcp = cred[1][tid] + cred[1][256 + tid] + cred[1][512 + tid] + cred[1][768 + tid];
        cpart [((size_t)tile * NB + b) * ND + tid] = pc;
        cppart[((size_t)tile * NB + b) * ND + tid] = pcp;
    }

    // ---- phase 6: alpha @ w_s^T via MFMA -> xfer ----
    {
        f32x4 acc2[2][4];
        #pragma unroll
        for (int mt = 0; mt < 2; ++mt)
            #pragma unroll
            for (int nt = 0; nt < 4; ++nt)
                acc2[mt][nt] = (f32x4)0.f;
        #pragma unroll
        for (int ks = 0; ks < 8; ++ks) {
            int kb = ks * 32 + g * 8;
            bf16x8 afr[2];
            #pragma unroll
            for (int mt = 0; mt < 2; ++mt) {
                int row = mt * 16 + c15;
                afr[mt] = *(const bf16x8*)(tb + ((row * 512 + kb * 2) ^ ((row & 7) << 4)));
            }
            #pragma unroll
            for (int nt = 0; nt < 4; ++nt) {
                int o = o0 + nt * 16 + c15;
                bf16x8 bfr = *(const bf16x8*)(w_s_bf + (size_t)o * ND + kb);
                #pragma unroll
                for (int mt = 0; mt < 2; ++mt)
                    acc2[mt][nt] = __builtin_amdgcn_mfma_f32_16x16x32_bf16(afr[mt], bfr, acc2[mt][nt], 0, 0, 0);
            }
        }
        __syncthreads();   // xfer alpha fully consumed in 5a; safe to overwrite
        #pragma unroll
        for (int mt = 0; mt < 2; ++mt)
            #pragma unroll
            for (int reg = 0; reg < 4; ++reg) {
                int r = mt * 16 + g * 4 + reg;
                #pragma unroll
                for (int nt = 0; nt < 4; ++nt)
                    xfer[r * XS + o0 + nt * 16 + c15] = acc2[mt][nt][reg];
            }
    }
    __syncthreads();

    // ---- phase 7: bsum = bsv + xfer (float4 pure store) ----
    #pragma unroll
    for (int i = 0; i < 8; ++i) {
        int r = wv + 4 * i;
        float4 x4 = *(const float4*)&xfer[r * XS + 4 * c];
        float4 o4;
        o4.x = bsv4[i].x + x4.x;
        o4.y = bsv4[i].y + x4.y;
        o4.z = bsv4[i].z + x4.z;
        o4.w = bsv4[i].w + x4.w;
        *(float4*)(bsum + ((size_t)(b * NF + f0 + r)) * ND + 4 * c) = o4;
    }
}

extern "C" void kernel_launch(void* const* d_in, const int* in_sizes, int n_in,
                              void* d_out, int out_size, void* d_ws, size_t ws_size,
                              hipStream_t stream) {
    const float* fin  = (const float*)d_in[0];
    const int*   ids  = (const int*)  d_in[1];
    const float* emb  = (const float*)d_in[2];
    const float* w_e  = (const float*)d_in[3];
    const float* w_h  = (const float*)d_in[4];
    const float* w_f  = (const float*)d_in[5];
    const float* w_q  = (const float*)d_in[6];
    const float* w_s  = (const float*)d_in[7];
    const float* w_g  = (const float*)d_in[8];
    const float* w_ih = (const float*)d_in[9];
    const float* w_hh = (const float*)d_in[10];
    float* out = (float*)d_out;
    float* ws  = (float*)d_ws;

    size_t off = 0;
    float* q      = ws + off; off += (size_t)NF * ND;
    float* qwq    = ws + off; off += (size_t)NF * ND;
    float* bsum   = ws + off; off += (size_t)NB * NF * ND;
    float* h0     = ws + off; off += (size_t)NB * ND;
    float* h1     = ws + off; off += (size_t)NB * ND;
    float* cell0  = ws + off; off += (size_t)NB * ND;
    float* cell1  = ws + off; off += (size_t)NB * ND;
    float* gatesT = ws + off; off += (size_t)NB * 1024;
    float* cpart  = ws + off; off += (size_t)NTILE * NB * ND;
    float* cppart = ws + off; off += (size_t)NTILE * NB * ND;
    float* w_hT   = ws + off; off += (size_t)ND * ND;
    float* w_gT   = ws + off; off += (size_t)512 * ND;
    short* w_e_bf = (short*)(ws + off); off += (size_t)ND * ND / 2;
    short* w_s_bf = (short*)(ws + off); off += (size_t)ND * ND / 2;

    float* hbuf[2]    = { h0, h1 };
    float* cellbuf[2] = { cell0, cell1 };

    hipMemsetAsync(h0, 0, sizeof(float) * NB * ND, stream);
    hipMemsetAsync(cell0, 0, sizeof(float) * NB * ND, stream);

    pe_kernel<<<NF, ND, 0, stream>>>(q);
    wcvt_kernel<<<ND * ND / 256, 256, 0, stream>>>(w_e, w_e_bf, ND * ND);
    wcvt_kernel<<<ND * ND / 256, 256, 0, stream>>>(w_s, w_s_bf, ND * ND);
    wprep_kernel<<<512, ND, 0, stream>>>(w_h, w_g, w_hT, w_gT);
    qwq_kernel<<<NF, ND, 0, stream>>>(q, w_q, qwq);
    base_kernel<<<NB * NTILE, ND, 0, stream>>>(fin, w_f, qwq, bsum);

    const size_t gates_lds = (size_t)(8 * 768 + NB * ZSTRIDE) * sizeof(float);  // 123008 B

    for (int t = 0; t < NT; ++t) {
        int mode = (t > 0) ? 3 : 1;
        int p = t & 1;
        gates_kernel<<<160, ND, gates_lds, stream>>>(t, mode, ids, emb, cpart, cppart, hbuf[p],
                                                     w_ih, w_hh, w_gT, gatesT, out);
        attn_step_kernel<<<NB * NTILE, ND, 0, stream>>>(bsum, fin, q, gatesT,
                                                        cellbuf[p], cellbuf[p ^ 1], hbuf[p ^ 1],
                                                        w_hT, w_e_bf, w_s_bf, cpart, cppart);
    }
    // final pred for t = NT-1 (h(NT-1) lives in hbuf[NT&1] = hbuf[0])
    gates_kernel<<<160, ND, gates_lds, stream>>>(NT, 2, ids, emb, cpart, cppart, hbuf[0],
                                                 w_ih, w_hh, w_gT, gatesT, out);
}